// Round 8
// baseline (289.520 us; speedup 1.0000x reference)
//
#include <hip/hip_runtime.h>

// PhotometricLoss: fused warp + SSIM(3x3 avgpool, zero-pad) + L1 + masked mean.
// B=8, C=3, H=720, W=1280 fp32.
//
// R8 = R3 skeleton (1 px/lane, register ring of horizontal 3-sums, depth-1
// prefetch, branchless edges) with the bilinear right-gather converted from
// 6 per-lane-DIVERGENT global loads (TA/L1 request-path congestion -- the
// invariant ~40% VALUBusy ceiling of R1-R7) into: 1 coalesced right load per
// channel (lane loads right[wb+lane], wb = obase-6) + 2 dynamic __shfl
// (ds_bpermute, idle LDS pipe). Window covers i0,i1 for |disp|<=4; rarer
// lanes take an exact predicated global-load fallback under __any (skipped
// ~99.6% of steps). 52 useful output cols per wave; x,y computed on lanes
// 0..53 (col = obase-1+lane), outputs on lanes 1..52.

#define P_ALPHA 0.85f
#define P_C1 1e-4f
#define P_C2 9e-4f

constexpr int W_ = 1280, H_ = 720, HW_ = W_ * H_;
constexpr int UCOLS = 52;          // useful output columns per strip
constexpr int VLANES = 54;         // lanes computing valid x,y (cols obase-1 .. obase+52)
constexpr int RPW   = 12;          // output rows per wave task
constexpr int XS    = 25;          // col strips (25*52 = 1300 >= 1280)

__global__ __launch_bounds__(256)
void photo_loss_kernel(const float* __restrict__ disp,
                       const float* __restrict__ left,
                       const float* __restrict__ right,
                       float* __restrict__ acc)   // acc[0]=sum(pv), acc[1]=sum(v)
{
    __shared__ float redpv[4], redv[4];

    const int tid  = threadIdx.x;
    const int lane = tid & 63;
    const int wv   = tid >> 6;
    const int b    = blockIdx.z;
    const int obase = blockIdx.x * UCOLS;
    const int col   = obase - 1 + lane;            // value col this lane computes
    const int wb    = obase - 6;                   // right-window origin (px)
    const int r0    = (blockIdx.y * 4 + wv) * RPW;
    const float wm1 = (float)(W_ - 1);

    const float* __restrict__ dispb = disp + (size_t)b * HW_;
    const float* __restrict__ L0 = left  + (size_t)(b * 3 + 0) * HW_;
    const float* __restrict__ L1 = left  + (size_t)(b * 3 + 1) * HW_;
    const float* __restrict__ L2 = left  + (size_t)(b * 3 + 2) * HW_;
    const float* __restrict__ R0 = right + (size_t)(b * 3 + 0) * HW_;
    const float* __restrict__ R1 = right + (size_t)(b * 3 + 1) * HW_;
    const float* __restrict__ R2 = right + (size_t)(b * 3 + 2) * HW_;

    const int   colC = min(max(col, 0), W_ - 1);                 // clamped addr col (disp/left)
    const int   wq   = min(max(wb + lane, 0), W_ - 1);           // clamped addr col (right window)
    const float colv = (col >= 0 && col < W_) ? 1.f : 0.f;
    const float ocm  = (lane >= 1 && lane <= UCOLS && col < W_) ? 1.f : 0.f;
    const bool  vlane = (lane < VLANES);

    // 3-row register rings (static indices after unroll)
    float rsx[3][3], rsy[3][3], rsxx[3][3], rsyy[3][3], rsxy[3][3];
    float l1r[3], vr[3];
    float sum_pv = 0.f, sum_v = 0.f;

    auto emit = [&](int cs) {
        const float inv9 = 1.f / 9.f;
        float ssim_sum = 0.f;
        #pragma unroll
        for (int c = 0; c < 3; ++c) {
            float mu_x = (rsx[c][0]  + rsx[c][1]  + rsx[c][2])  * inv9;
            float mu_y = (rsy[c][0]  + rsy[c][1]  + rsy[c][2])  * inv9;
            float exx  = (rsxx[c][0] + rsxx[c][1] + rsxx[c][2]) * inv9;
            float eyy  = (rsyy[c][0] + rsyy[c][1] + rsyy[c][2]) * inv9;
            float exy  = (rsxy[c][0] + rsxy[c][1] + rsxy[c][2]) * inv9;
            float sig_x  = fmaxf(exx - mu_x * mu_x, 0.f);
            float sig_y  = fmaxf(eyy - mu_y * mu_y, 0.f);
            float sig_xy = exy - mu_x * mu_y;
            float n  = (2.f * mu_x * mu_y + P_C1) * (2.f * sig_xy + P_C2);
            float dd = (mu_x * mu_x + mu_y * mu_y + P_C1) * (sig_x + sig_y + P_C2);
            float s  = (1.f - n * __builtin_amdgcn_rcpf(dd)) * 0.5f;  // dd >= C1*C2 > 0
            s = fminf(fmaxf(s, 0.f), 1.f);
            ssim_sum += s;
        }
        float photo = P_ALPHA * (ssim_sum * (1.f / 3.f))
                    + (1.f - P_ALPHA) * (l1r[cs] * (1.f / 3.f));
        sum_pv += photo * vr[cs] * ocm;
        sum_v  += vr[cs] * ocm;
    };

    // ---- prologue: row r0-1 (clamped) -> disp/left regs + right-window regs ----
    float dC, xC0, xC1, xC2, rw0, rw1, rw2;
    {
        const int rc  = max(r0 - 1, 0);
        const int off = rc * W_ + colC;
        dC = dispb[off]; xC0 = L0[off]; xC1 = L1[off]; xC2 = L2[off];
        const int wo = rc * W_ + wq;
        rw0 = R0[wo]; rw1 = R1[wo]; rw2 = R2[wo];
    }

    #pragma unroll
    for (int j = 0; j <= RPW + 2; ++j) {
        const int s = j % 3;                 // ring slot (compile-time)
        const int r = r0 - 1 + j;            // row gathered this step
        if (j <= RPW + 1) {
            const int   rc = min(max(r, 0), H_ - 1);
            const float rv = (r >= 0 && r < H_) ? 1.f : 0.f;
            const float m  = rv * colv;

            // ---- prefetch row r+1 (disp/left at colC, right window at wq) ----
            float dN = 0.f, xN0 = 0.f, xN1 = 0.f, xN2 = 0.f;
            float nw0 = 0.f, nw1 = 0.f, nw2 = 0.f;
            if (j <= RPW) {
                const int rn   = min(max(r + 1, 0), H_ - 1);
                const int offn = rn * W_ + colC;
                dN = dispb[offn];
                xN0 = L0[offn]; xN1 = L1[offn]; xN2 = L2[offn];
                const int won = rn * W_ + wq;
                nw0 = R0[won]; nw1 = R1[won]; nw2 = R2[won];
            }

            // ---- gather row r via wave-window shuffles (dC, rw* in regs) ----
            const float xsm = (float)col - dC;
            const float xcl = fminf(fmaxf(xsm, 0.f), wm1);
            const float xf  = floorf(xcl);
            const float fr  = xcl - xf;
            const int   i0  = (int)xf;
            const int   i1  = min(i0 + 1, W_ - 1);
            const int   sl0 = i0 - wb;
            const int   sl1 = i1 - wb;
            const int   sl0c = min(max(sl0, 0), 63);
            const int   sl1c = min(max(sl1, 0), 63);
            float g00 = __shfl(rw0, sl0c, 64), g01 = __shfl(rw0, sl1c, 64);
            float g10 = __shfl(rw1, sl0c, 64), g11 = __shfl(rw1, sl1c, 64);
            float g20 = __shfl(rw2, sl0c, 64), g21 = __shfl(rw2, sl1c, 64);
            // exact fallback for out-of-window lanes (|disp|>4): ~never taken
            {
                const bool outb = vlane && (m > 0.f) &&
                                  (((unsigned)sl0 > 63u) || ((unsigned)sl1 > 63u));
                if (__any(outb ? 1 : 0)) {
                    if (outb) {
                        const int ro = rc * W_;
                        g00 = R0[ro + i0]; g01 = R0[ro + i1];
                        g10 = R1[ro + i0]; g11 = R1[ro + i1];
                        g20 = R2[ro + i0]; g21 = R2[ro + i1];
                    }
                }
            }

            // ---- emit center r-2 (pure VALU, ring only) ----
            if (j >= 3) emit((s + 1) % 3);

            // ---- consume: warp values, static +-1 shuffles, ring slot s ----
            const float omf = 1.f - fr;
            const float y0 = (omf * g00 + fr * g01) * m;
            const float y1 = (omf * g10 + fr * g11) * m;
            const float y2 = (omf * g20 + fr * g21) * m;
            const float x0 = xC0 * m;
            const float x1 = xC1 * m;
            const float x2 = xC2 * m;

            float xl, xr, yl, yr;
            xl = __shfl_up(x0, 1, 64); xr = __shfl_down(x0, 1, 64);
            yl = __shfl_up(y0, 1, 64); yr = __shfl_down(y0, 1, 64);
            rsx[0][s]  = xl + x0 + xr;
            rsy[0][s]  = yl + y0 + yr;
            rsxx[0][s] = xl * xl + x0 * x0 + xr * xr;
            rsyy[0][s] = yl * yl + y0 * y0 + yr * yr;
            rsxy[0][s] = xl * yl + x0 * y0 + xr * yr;

            xl = __shfl_up(x1, 1, 64); xr = __shfl_down(x1, 1, 64);
            yl = __shfl_up(y1, 1, 64); yr = __shfl_down(y1, 1, 64);
            rsx[1][s]  = xl + x1 + xr;
            rsy[1][s]  = yl + y1 + yr;
            rsxx[1][s] = xl * xl + x1 * x1 + xr * xr;
            rsyy[1][s] = yl * yl + y1 * y1 + yr * yr;
            rsxy[1][s] = xl * yl + x1 * y1 + xr * yr;

            xl = __shfl_up(x2, 1, 64); xr = __shfl_down(x2, 1, 64);
            yl = __shfl_up(y2, 1, 64); yr = __shfl_down(y2, 1, 64);
            rsx[2][s]  = xl + x2 + xr;
            rsy[2][s]  = yl + y2 + yr;
            rsxx[2][s] = xl * xl + x2 * x2 + xr * xr;
            rsyy[2][s] = yl * yl + y2 * y2 + yr * yr;
            rsxy[2][s] = xl * yl + x2 * y2 + xr * yr;

            l1r[s] = fabsf(x0 - y0) + fabsf(x1 - y1) + fabsf(x2 - y2);
            vr[s]  = (xsm > 0.f && xsm < wm1) ? 1.f : 0.f;

            // rotate pipeline
            dC = dN; xC0 = xN0; xC1 = xN1; xC2 = xN2;
            rw0 = nw0; rw1 = nw1; rw2 = nw2;
        } else {
            emit((s + 1) % 3);               // final center r0+RPW-1
        }
    }

    // wave reduce (64 lanes) then cross-wave via tiny LDS
    #pragma unroll
    for (int off = 32; off > 0; off >>= 1) {
        sum_pv += __shfl_down(sum_pv, off, 64);
        sum_v  += __shfl_down(sum_v,  off, 64);
    }
    if (lane == 0) { redpv[wv] = sum_pv; redv[wv] = sum_v; }
    __syncthreads();
    if (tid == 0) {
        atomicAdd(&acc[0], redpv[0] + redpv[1] + redpv[2] + redpv[3]);
        atomicAdd(&acc[1], redv[0]  + redv[1]  + redv[2]  + redv[3]);
    }
}

__global__ void photo_loss_finalize(const float* __restrict__ acc,
                                    float* __restrict__ out)
{
    out[0] = acc[0] / fmaxf(acc[1], 1.f);
}

extern "C" void kernel_launch(void* const* d_in, const int* in_sizes, int n_in,
                              void* d_out, int out_size, void* d_ws, size_t ws_size,
                              hipStream_t stream)
{
    const float* disp  = (const float*)d_in[0];
    const float* left  = (const float*)d_in[1];
    const float* right = (const float*)d_in[2];
    float* out = (float*)d_out;
    float* acc = (float*)d_ws;

    hipMemsetAsync(acc, 0, 2 * sizeof(float), stream);

    // x: 25 strips of 52 cols; y: 720 / (4 waves * 12 rows) = 15; z: batch
    dim3 grid(XS, H_ / (4 * RPW), 8);
    dim3 block(256);
    photo_loss_kernel<<<grid, block, 0, stream>>>(disp, left, right, acc);
    photo_loss_finalize<<<1, 1, 0, stream>>>(acc, out);
}